// Round 7
// baseline (430.759 us; speedup 1.0000x reference)
//
#include <hip/hip_runtime.h>
#include <hip/hip_cooperative_groups.h>
#include <math.h>

namespace cg = cooperative_groups;

#define NPTS 4096
#define BLK 256
#define NUNITS 16                    // 8 batches * 2 directions
#define CHUNKS 8                     // target chunks per unit
#define CSZ 512                      // targets per chunk
#define TILES 16                     // 32-target tiles per chunk
#define QGRP 512                     // queries per block (phase 1)
#define QGRPS 8                      // query groups per unit
#define GRID (NUNITS * QGRPS * CHUNKS)   // 1024 blocks
#define CNT 12288.0f                 // N*D elements per std
#define KEY_WORDS (NUNITS * CHUNKS * NPTS)   // 524288 u32 = 2 MB

typedef _Float16 half8 __attribute__((ext_vector_type(8)));
typedef float f32x16 __attribute__((ext_vector_type(16)));

__device__ __forceinline__ unsigned umin2(unsigned a, unsigned b) { return a < b ? a : b; }
__device__ __forceinline__ float fmin3(float a, float b, float c) {
  return fminf(fminf(a, b), c);      // fuses to v_min3_f32
}

// min over the 16 f32 accumulator regs of one 32x32 MFMA result
__device__ __forceinline__ float tilemin16(const f32x16 d) {
  const float a0 = fmin3(d[0],  d[1],  d[2]);
  const float a1 = fmin3(d[3],  d[4],  d[5]);
  const float a2 = fmin3(d[6],  d[7],  d[8]);
  const float a3 = fmin3(d[9],  d[10], d[11]);
  const float a4 = fmin3(d[12], d[13], d[14]);
  return fminf(fmin3(a0, a1, a2), fmin3(a3, a4, d[15]));
}

// ---------------------------------------------------------------------------
// Phase 1: per (unit, qgrp, chunk) hierarchical argmin keys (proven r3-r6).
// fp16-split d2 via ONE 32x32x16 f16 MFMA per 32-target tile:
//  k0-2: bh*(-2ah)  k3-5: bl*(-2ah)  k6-8: bh*(-2al)
//  k9,10: b2{h,l}*1  k11,12: 1*a2{h,l}  k13-15: 0
// Hot loop tracks only (trunc tile-min | tile-id); exact resolve in phase 2.
// ---------------------------------------------------------------------------
__device__ __forceinline__ void phase1_keys(
    const float* __restrict__ x, const float* __restrict__ y,
    unsigned* __restrict__ keys, const int bid, const int tid,
    half8* Ap, half8* Bq) {
  const int unit  = bid >> 6;          // 8 qgrps * 8 chunks = 64 blocks/unit
  const int qg    = (bid >> 3) & 7;
  const int chunk = bid & 7;
  const int b = unit >> 1, dir = unit & 1;
  const float* __restrict__ Q = (dir ? y : x) + (size_t)b * NPTS * 3;  // queries
  const float* __restrict__ T = (dir ? x : y) + (size_t)b * NPTS * 3;  // targets

  const _Float16 one  = (_Float16)1.0f;
  const _Float16 zero = (_Float16)0.0f;
  const _Float16 n2   = (_Float16)(-2.0f);

  // ---- pack two target rows + two query columns per thread ----
  #pragma unroll
  for (int k = 0; k < 2; ++k) {
    const int i = tid + k * BLK;       // 0..511
    {
      const int tg = chunk * CSZ + i;
      const float bx = T[3 * tg], by = T[3 * tg + 1], bz = T[3 * tg + 2];
      const float b2 = fmaf(bx, bx, fmaf(by, by, bz * bz));
      const _Float16 bh0 = (_Float16)bx, bh1 = (_Float16)by, bh2 = (_Float16)bz;
      const _Float16 bl0 = (_Float16)(bx - (float)bh0);
      const _Float16 bl1 = (_Float16)(by - (float)bh1);
      const _Float16 bl2 = (_Float16)(bz - (float)bh2);
      const _Float16 s2h = (_Float16)b2;
      const _Float16 s2l = (_Float16)(b2 - (float)s2h);
      half8 lo, hi;
      lo[0] = bh0; lo[1] = bh1; lo[2] = bh2; lo[3] = bl0;
      lo[4] = bl1; lo[5] = bl2; lo[6] = bh0; lo[7] = bh1;
      hi[0] = bh2; hi[1] = s2h; hi[2] = s2l; hi[3] = one;
      hi[4] = one; hi[5] = zero; hi[6] = zero; hi[7] = zero;
      Ap[i]       = lo;
      Ap[CSZ + i] = hi;
    }
    {
      const int qq = qg * QGRP + i;
      const float ax = Q[3 * qq], ay = Q[3 * qq + 1], az = Q[3 * qq + 2];
      const float a2 = fmaf(ax, ax, fmaf(ay, ay, az * az));
      const _Float16 ah0 = (_Float16)ax, ah1 = (_Float16)ay, ah2 = (_Float16)az;
      const _Float16 al0 = (_Float16)(ax - (float)ah0);
      const _Float16 al1 = (_Float16)(ay - (float)ah1);
      const _Float16 al2 = (_Float16)(az - (float)ah2);
      const _Float16 a2h = (_Float16)a2;
      const _Float16 a2l = (_Float16)(a2 - (float)a2h);
      half8 lo, hi;
      lo[0] = n2 * ah0; lo[1] = n2 * ah1; lo[2] = n2 * ah2; lo[3] = n2 * ah0;
      lo[4] = n2 * ah1; lo[5] = n2 * ah2; lo[6] = n2 * al0; lo[7] = n2 * al1;
      hi[0] = n2 * al2; hi[1] = one; hi[2] = one; hi[3] = a2h;
      hi[4] = a2l; hi[5] = zero; hi[6] = zero; hi[7] = zero;
      Bq[i]        = lo;
      Bq[QGRP + i] = hi;
    }
  }
  __syncthreads();

  const int lane = tid & 63, w = tid >> 6, ln = lane & 31, hi5 = lane >> 5;
  // wave w owns queries w*128 .. w*128+127 (4 column tiles)
  const half8 bf0 = Bq[hi5 * QGRP + w * 128 + ln];
  const half8 bf1 = Bq[hi5 * QGRP + w * 128 + 32 + ln];
  const half8 bf2 = Bq[hi5 * QGRP + w * 128 + 64 + ln];
  const half8 bf3 = Bq[hi5 * QGRP + w * 128 + 96 + ln];

  f32x16 Z;
  #pragma unroll
  for (int r = 0; r < 16; ++r) Z[r] = 0.0f;

  unsigned kacc0 = 0xFFFFFFFFu, kacc1 = 0xFFFFFFFFu;
  unsigned kacc2 = 0xFFFFFFFFu, kacc3 = 0xFFFFFFFFu;
  const unsigned pbase = (unsigned)(chunk * TILES);

  #pragma unroll 4
  for (int t = 0; t < TILES; ++t) {
    const half8 af = Ap[hi5 * CSZ + t * 32 + ln];
    const f32x16 d0 = __builtin_amdgcn_mfma_f32_32x32x16_f16(af, bf0, Z, 0, 0, 0);
    const f32x16 d1 = __builtin_amdgcn_mfma_f32_32x32x16_f16(af, bf1, Z, 0, 0, 0);
    const f32x16 d2 = __builtin_amdgcn_mfma_f32_32x32x16_f16(af, bf2, Z, 0, 0, 0);
    const f32x16 d3 = __builtin_amdgcn_mfma_f32_32x32x16_f16(af, bf3, Z, 0, 0, 0);
    const unsigned pay = pbase + (unsigned)t;
    kacc0 = umin2(kacc0, (__float_as_uint(tilemin16(d0)) & 0xFFFFF000u) | pay);
    kacc1 = umin2(kacc1, (__float_as_uint(tilemin16(d1)) & 0xFFFFF000u) | pay);
    kacc2 = umin2(kacc2, (__float_as_uint(tilemin16(d2)) & 0xFFFFF000u) | pay);
    kacc3 = umin2(kacc3, (__float_as_uint(tilemin16(d3)) & 0xFFFFF000u) | pay);
  }

  // merge the two 16-row halves of each tile (key carries tile-id only)
  kacc0 = umin2(kacc0, (unsigned)__shfl_xor((int)kacc0, 32));
  kacc1 = umin2(kacc1, (unsigned)__shfl_xor((int)kacc1, 32));
  kacc2 = umin2(kacc2, (unsigned)__shfl_xor((int)kacc2, 32));
  kacc3 = umin2(kacc3, (unsigned)__shfl_xor((int)kacc3, 32));

  if (lane < 32) {
    const unsigned kb = (unsigned)((unit * CHUNKS + chunk) << 12);
    const unsigned q0 = (unsigned)(qg * QGRP + w * 128 + ln);
    keys[kb | q0]        = kacc0;
    keys[kb | (q0 + 32)] = kacc1;
    keys[kb | (q0 + 64)] = kacc2;
    keys[kb | (q0 + 96)] = kacc3;
  }
}

// ---------------------------------------------------------------------------
// Phase 2: 64 queries per block (wave 0): min the 8 chunk keys -> winning
// 32-target tile; exact fp32 rescan (first-index tie-break); residual;
// wave-reduced (sum, sumsq) partial -> partials[bid].
// ---------------------------------------------------------------------------
__device__ __forceinline__ void phase2_resolve(
    const float* __restrict__ x, const float* __restrict__ y,
    const unsigned* __restrict__ keys, float2* __restrict__ partials,
    const int bid, const int tid) {
  if (tid >= 64) return;
  const int qid  = bid * 64 + tid;
  const int unit = qid >> 12;
  const int q    = qid & 4095;
  const int b = unit >> 1, dir = unit & 1;
  const float* __restrict__ Q = (dir ? y : x) + (size_t)b * NPTS * 3;
  const float* __restrict__ T = (dir ? x : y) + (size_t)b * NPTS * 3;

  unsigned bk = 0xFFFFFFFFu;
  #pragma unroll
  for (int c = 0; c < CHUNKS; ++c) {
    bk = umin2(bk, keys[((unsigned)(unit * CHUNKS + c) << 12) | (unsigned)q]);
  }
  const int tbase = (int)(bk & 4095u) * 32;   // payload = chunk*16 + tile

  const float qx = Q[3 * q], qy = Q[3 * q + 1], qz = Q[3 * q + 2];
  unsigned best = 0xFFFFFFFFu;
  #pragma unroll 8
  for (int i = 0; i < 32; ++i) {
    const int j = tbase + i;
    const float dx = qx - T[3 * j];
    const float dy = qy - T[3 * j + 1];
    const float dz = qz - T[3 * j + 2];
    const float d2 = fmaf(dx, dx, fmaf(dy, dy, dz * dz));
    best = umin2(best, (__float_as_uint(d2) & 0xFFFFFFE0u) | (unsigned)i);
  }
  const int j = tbase + (int)(best & 31u);

  const float rx = qx - T[3 * j];
  const float ry = qy - T[3 * j + 1];
  const float rz = qz - T[3 * j + 2];
  float s  = rx + ry + rz;
  float ss = fmaf(rx, rx, fmaf(ry, ry, rz * rz));

  #pragma unroll
  for (int off = 32; off > 0; off >>= 1) {
    s  += __shfl_down(s, off);
    ss += __shfl_down(ss, off);
  }
  if (tid == 0) partials[bid] = make_float2(s, ss);
}

// ---------------------------------------------------------------------------
// Phase 3 (one block): reduce 1024 partials -> 16 sigma -> mean of per-batch
// max. Deterministic fixed-order sums.
// ---------------------------------------------------------------------------
__device__ __forceinline__ void phase3_finalize(
    const float2* __restrict__ partials, float* __restrict__ out,
    const int tid, float2* sh2, float* sig) {
  #pragma unroll
  for (int k = 0; k < 4; ++k) sh2[tid + k * BLK] = partials[tid + k * BLK];
  __syncthreads();
  if (tid < NUNITS) {
    float S = 0.f, SS = 0.f;
    for (int i = 0; i < 64; ++i) {   // 64 blocks per unit
      S  += sh2[tid * 64 + i].x;
      SS += sh2[tid * 64 + i].y;
    }
    const float var = (SS - S * S / CNT) / (CNT - 1.0f);
    sig[tid] = sqrtf(fmaxf(var, 0.0f));
  }
  __syncthreads();
  if (tid == 0) {
    float acc = 0.f;
    #pragma unroll
    for (int b2 = 0; b2 < 8; ++b2) acc += fmaxf(sig[2 * b2], sig[2 * b2 + 1]);
    out[0] = acc * 0.125f;
  }
}

// ---------------------------------------------------------------------------
// Single cooperative kernel: keys -> grid.sync -> resolve -> grid.sync ->
// finalize. __threadfence() (agent scope) around syncs for cross-XCD L2
// visibility of plain stores (G16).
// ---------------------------------------------------------------------------
__global__ __launch_bounds__(BLK, 4) void fused_coop_kernel(
    const float* __restrict__ x, const float* __restrict__ y,
    unsigned* __restrict__ keys, float2* __restrict__ partials,
    float* __restrict__ out) {
  __shared__ __align__(16) unsigned char lds_raw[32 * 1024];   // 32 KB
  half8* Ap = (half8*)lds_raw;                  // 16 KB (phase 1)
  half8* Bq = (half8*)(lds_raw + 16 * 1024);    // 16 KB (phase 1)

  cg::grid_group grid = cg::this_grid();
  const int bid = blockIdx.x, tid = threadIdx.x;

  phase1_keys(x, y, keys, bid, tid, Ap, Bq);
  __threadfence();
  grid.sync();
  __threadfence();
  phase2_resolve(x, y, keys, partials, bid, tid);
  __threadfence();
  grid.sync();
  __threadfence();
  if (bid == 0) {
    phase3_finalize(partials, out, tid,
                    (float2*)lds_raw, (float*)(lds_raw + 16 * 1024));
  }
}

// ---------------------------------------------------------------------------
// Fallback (plain dispatches of the same phases) if cooperative launch fails.
// ---------------------------------------------------------------------------
__global__ __launch_bounds__(BLK, 4) void keys_fb_kernel(
    const float* __restrict__ x, const float* __restrict__ y,
    unsigned* __restrict__ keys) {
  __shared__ __align__(16) unsigned char lds_raw[32 * 1024];
  phase1_keys(x, y, keys, blockIdx.x, threadIdx.x,
              (half8*)lds_raw, (half8*)(lds_raw + 16 * 1024));
}

__global__ __launch_bounds__(64) void resolve_fb_kernel(
    const float* __restrict__ x, const float* __restrict__ y,
    const unsigned* __restrict__ keys, float2* __restrict__ partials) {
  phase2_resolve(x, y, keys, partials, blockIdx.x, threadIdx.x);
}

__global__ __launch_bounds__(BLK) void finalize_fb_kernel(
    const float2* __restrict__ partials, float* __restrict__ out) {
  __shared__ float2 sh2[GRID];
  __shared__ float sig[NUNITS];
  phase3_finalize(partials, out, threadIdx.x, sh2, sig);
}

// ---------------------------------------------------------------------------
extern "C" void kernel_launch(void* const* d_in, const int* in_sizes, int n_in,
                              void* d_out, int out_size, void* d_ws, size_t ws_size,
                              hipStream_t stream) {
  const float* x = (const float*)d_in[0];
  const float* y = (const float*)d_in[1];
  float* out = (float*)d_out;

  unsigned* keys = (unsigned*)d_ws;                               // 2 MB
  float2* partials = (float2*)((char*)d_ws + (size_t)KEY_WORDS * 4);  // 8 KB

  void* args[5] = {(void*)&x, (void*)&y, (void*)&keys, (void*)&partials, (void*)&out};
  const hipError_t err = hipLaunchCooperativeKernel(
      (const void*)fused_coop_kernel, dim3(GRID), dim3(BLK), args, 0, stream);

  if (err != hipSuccess) {
    // deterministic fallback: same phases as 3 plain dispatches
    hipLaunchKernelGGL(keys_fb_kernel, dim3(GRID), dim3(BLK), 0, stream, x, y, keys);
    hipLaunchKernelGGL(resolve_fb_kernel, dim3(GRID), dim3(64), 0, stream,
                       x, y, keys, partials);
    hipLaunchKernelGGL(finalize_fb_kernel, dim3(1), dim3(BLK), 0, stream,
                       partials, out);
  }
}

// Round 8
// 373.377 us; speedup vs baseline: 1.1537x; 1.1537x over previous
//
#include <hip/hip_runtime.h>
#include <math.h>

#define NPTS 4096
#define BLK 256
#define NUNITS 16                    // 8 batches * 2 directions
#define CHUNKS 16                    // target chunks per unit
#define CSZ 256                      // targets per chunk
#define TILES 8                      // 32-target tiles per chunk
#define QGRP 256                     // queries per group
#define QGRPS 16                     // query groups per unit
#define GRID1 (NUNITS * QGRPS * CHUNKS)  // 4096 blocks
#define NGROUPS (NUNITS * QGRPS)         // 256 resolver groups
#define CNT 12288.0f                 // N*D elements per std
#define KEY_BYTES ((size_t)NUNITS * CHUNKS * NPTS * 4)   // 4 MB

typedef _Float16 half8 __attribute__((ext_vector_type(8)));
typedef float f32x16 __attribute__((ext_vector_type(16)));

__device__ __forceinline__ unsigned umin2(unsigned a, unsigned b) { return a < b ? a : b; }
__device__ __forceinline__ float fmin3(float a, float b, float c) {
  return fminf(fminf(a, b), c);      // fuses to v_min3_f32
}

// min over the 16 f32 accumulator regs of one 32x32 MFMA result
__device__ __forceinline__ float tilemin16(const f32x16 d) {
  const float a0 = fmin3(d[0],  d[1],  d[2]);
  const float a1 = fmin3(d[3],  d[4],  d[5]);
  const float a2 = fmin3(d[6],  d[7],  d[8]);
  const float a3 = fmin3(d[9],  d[10], d[11]);
  const float a4 = fmin3(d[12], d[13], d[14]);
  return fminf(fmin3(a0, a1, a2), fmin3(a3, a4, d[15]));
}

// ---------------------------------------------------------------------------
// ONE plain dispatch, three chained roles, no spinning:
//  A) every block: r5's keys phase for its (unit, qgrp, chunk).
//     fp16-split d2 via ONE 32x32x16 f16 MFMA per 32-target tile:
//       k0-2: bh*(-2ah)  k3-5: bl*(-2ah)  k6-8: bh*(-2al)
//       k9,10: b2{h,l}*1  k11,12: 1*a2{h,l}  k13-15: 0
//     Hot loop tracks (trunc tile-min | tile-id) only.
//  B) per 16-block group, the LAST arriver (mod-16 atomicInc ticket, self-
//     resetting from any initial value incl. 0xAA poison) resolves the
//     group's 256 queries: min of 16 chunk keys -> exact fp32 rescan of the
//     winning 32-target tile -> block-reduced (sum,sumsq) -> u64 atomicExch.
//  C) the LAST group resolver (mod-256 ticket) runs the deterministic
//     finalize: 16 sigmas -> mean of per-batch max.
// Memory ordering: plain key stores -> __threadfence (release) -> atomicInc;
// resolver: atomicInc observed -> __threadfence (acquire) -> ATOMIC key
// reads (r6-proven cross-XCD safe). Partials likewise atomic-only.
// ---------------------------------------------------------------------------
__global__ __launch_bounds__(BLK, 4) void fused_ticket_kernel(
    const float* __restrict__ x, const float* __restrict__ y,
    unsigned* __restrict__ keys, unsigned long long* __restrict__ partials,
    unsigned* __restrict__ gticks, unsigned* __restrict__ gtick,
    float* __restrict__ out) {
  __shared__ __align__(16) unsigned char lds_raw[16 * 1024];   // Ap 8K | Bq 8K
  half8* Ap = (half8*)lds_raw;                 // 2 planes x 256 targets
  half8* Bq = (half8*)(lds_raw + 8 * 1024);    // 2 planes x 256 queries
  __shared__ float wS[4], wSS[4];
  __shared__ unsigned lastsh;

  const int bid   = blockIdx.x;
  const int unit  = bid >> 8;          // 16 qgrps * 16 chunks = 256 blocks/unit
  const int qg    = (bid >> 4) & 15;
  const int chunk = bid & 15;
  const int grp   = bid >> 4;          // unit*16 + qg
  const int b = unit >> 1, dir = unit & 1;
  const float* __restrict__ Q = (dir ? y : x) + (size_t)b * NPTS * 3;  // queries
  const float* __restrict__ T = (dir ? x : y) + (size_t)b * NPTS * 3;  // targets

  const int tid = threadIdx.x;
  const _Float16 one  = (_Float16)1.0f;
  const _Float16 zero = (_Float16)0.0f;
  const _Float16 n2   = (_Float16)(-2.0f);

  // ======================= Phase A: keys (r5 verbatim) =====================
  {
    const int tg = chunk * CSZ + tid;
    const float bx = T[3 * tg], by = T[3 * tg + 1], bz = T[3 * tg + 2];
    const float b2 = fmaf(bx, bx, fmaf(by, by, bz * bz));
    const _Float16 bh0 = (_Float16)bx, bh1 = (_Float16)by, bh2 = (_Float16)bz;
    const _Float16 bl0 = (_Float16)(bx - (float)bh0);
    const _Float16 bl1 = (_Float16)(by - (float)bh1);
    const _Float16 bl2 = (_Float16)(bz - (float)bh2);
    const _Float16 s2h = (_Float16)b2;
    const _Float16 s2l = (_Float16)(b2 - (float)s2h);
    half8 lo, hi;
    lo[0] = bh0; lo[1] = bh1; lo[2] = bh2; lo[3] = bl0;
    lo[4] = bl1; lo[5] = bl2; lo[6] = bh0; lo[7] = bh1;
    hi[0] = bh2; hi[1] = s2h; hi[2] = s2l; hi[3] = one;
    hi[4] = one; hi[5] = zero; hi[6] = zero; hi[7] = zero;
    Ap[tid]       = lo;
    Ap[CSZ + tid] = hi;
  }
  {
    const int qq = qg * QGRP + tid;
    const float ax = Q[3 * qq], ay = Q[3 * qq + 1], az = Q[3 * qq + 2];
    const float a2 = fmaf(ax, ax, fmaf(ay, ay, az * az));
    const _Float16 ah0 = (_Float16)ax, ah1 = (_Float16)ay, ah2 = (_Float16)az;
    const _Float16 al0 = (_Float16)(ax - (float)ah0);
    const _Float16 al1 = (_Float16)(ay - (float)ah1);
    const _Float16 al2 = (_Float16)(az - (float)ah2);
    const _Float16 a2h = (_Float16)a2;
    const _Float16 a2l = (_Float16)(a2 - (float)a2h);
    half8 lo, hi;
    lo[0] = n2 * ah0; lo[1] = n2 * ah1; lo[2] = n2 * ah2; lo[3] = n2 * ah0;
    lo[4] = n2 * ah1; lo[5] = n2 * ah2; lo[6] = n2 * al0; lo[7] = n2 * al1;
    hi[0] = n2 * al2; hi[1] = one; hi[2] = one; hi[3] = a2h;
    hi[4] = a2l; hi[5] = zero; hi[6] = zero; hi[7] = zero;
    Bq[tid]        = lo;
    Bq[QGRP + tid] = hi;
  }
  __syncthreads();

  const int lane = tid & 63, w = tid >> 6, ln = lane & 31, hi5 = lane >> 5;
  const half8 bf0 = Bq[hi5 * QGRP + w * 64 + ln];
  const half8 bf1 = Bq[hi5 * QGRP + w * 64 + 32 + ln];

  f32x16 Z;
  #pragma unroll
  for (int r = 0; r < 16; ++r) Z[r] = 0.0f;

  unsigned kacc0 = 0xFFFFFFFFu, kacc1 = 0xFFFFFFFFu;
  const unsigned pbase = (unsigned)(chunk * TILES);

  #pragma unroll
  for (int t = 0; t < TILES; ++t) {
    const half8 af = Ap[hi5 * CSZ + t * 32 + ln];
    const f32x16 d0 = __builtin_amdgcn_mfma_f32_32x32x16_f16(af, bf0, Z, 0, 0, 0);
    const f32x16 d1 = __builtin_amdgcn_mfma_f32_32x32x16_f16(af, bf1, Z, 0, 0, 0);
    const unsigned pay = pbase + (unsigned)t;
    kacc0 = umin2(kacc0, (__float_as_uint(tilemin16(d0)) & 0xFFFFF000u) | pay);
    kacc1 = umin2(kacc1, (__float_as_uint(tilemin16(d1)) & 0xFFFFF000u) | pay);
  }

  kacc0 = umin2(kacc0, (unsigned)__shfl_xor((int)kacc0, 32));
  kacc1 = umin2(kacc1, (unsigned)__shfl_xor((int)kacc1, 32));

  if (lane < 32) {
    const unsigned kb = (unsigned)((unit * CHUNKS + chunk) << 12);
    const unsigned q0 = (unsigned)(qg * QGRP + w * 64 + ln);
    keys[kb | q0]        = kacc0;
    keys[kb | (q0 + 32)] = kacc1;
  }

  // ================= group ticket: am I the 16th arriver? ==================
  __threadfence();                                   // release keys stores
  if (tid == 0) lastsh = atomicInc(&gticks[grp], 15u);
  __syncthreads();
  if (lastsh != 14u) return;                         // 15/16 blocks exit here

  // ======================= Phase B: group resolve ==========================
  __threadfence();                                   // acquire
  const int q = ((grp & 15) << 8) + tid;
  unsigned bk = 0xFFFFFFFFu;
  #pragma unroll
  for (int c = 0; c < CHUNKS; ++c) {
    bk = umin2(bk, atomicAdd(&keys[((unsigned)(unit * CHUNKS + c) << 12) | (unsigned)q], 0u));
  }
  const int tbase = (int)(bk & 4095u) * 32;          // payload = chunk*8 + tile

  const float qx = Q[3 * q], qy = Q[3 * q + 1], qz = Q[3 * q + 2];
  unsigned best = 0xFFFFFFFFu;
  #pragma unroll 8
  for (int i = 0; i < 32; ++i) {
    const int j = tbase + i;
    const float dx = qx - T[3 * j];
    const float dy = qy - T[3 * j + 1];
    const float dz = qz - T[3 * j + 2];
    const float d2 = fmaf(dx, dx, fmaf(dy, dy, dz * dz));
    // exact fp32 in-tile argmin, first-index tie-break (5 low bits = row)
    best = umin2(best, (__float_as_uint(d2) & 0xFFFFFFE0u) | (unsigned)i);
  }
  const int j = tbase + (int)(best & 31u);

  const float rx = qx - T[3 * j];
  const float ry = qy - T[3 * j + 1];
  const float rz = qz - T[3 * j + 2];
  float s  = rx + ry + rz;
  float ss = fmaf(rx, rx, fmaf(ry, ry, rz * rz));

  #pragma unroll
  for (int off = 32; off > 0; off >>= 1) {
    s  += __shfl_down(s, off);
    ss += __shfl_down(ss, off);
  }
  if ((tid & 63) == 0) { wS[w] = s; wSS[w] = ss; }
  __syncthreads();

  if (tid == 0) {
    const float S  = wS[0]  + wS[1]  + wS[2]  + wS[3];
    const float SS = wSS[0] + wSS[1] + wSS[2] + wSS[3];
    const unsigned long long pv =
        ((unsigned long long)__float_as_uint(SS) << 32) | __float_as_uint(S);
    atomicExch(&partials[grp], pv);                  // device-scope publish
    __threadfence();
    lastsh = atomicInc(gtick, 255u);                 // global ticket
  }
  __syncthreads();
  if (lastsh != 254u) return;                        // 255/256 resolvers exit

  // ======================= Phase C: finalize ===============================
  __threadfence();                                   // acquire
  float2* sh2 = (float2*)lds_raw;                    // reuse LDS (2 KB)
  float*  sig = (float*)(lds_raw + 4 * 1024);
  {
    const unsigned long long pv = atomicAdd(&partials[tid], 0ULL);
    sh2[tid] = make_float2(__uint_as_float((unsigned)(pv & 0xFFFFFFFFull)),
                           __uint_as_float((unsigned)(pv >> 32)));
  }
  __syncthreads();

  if (tid < NUNITS) {
    float S = 0.f, SS = 0.f;
    #pragma unroll
    for (int i = 0; i < QGRPS; ++i) {
      S  += sh2[tid * QGRPS + i].x;
      SS += sh2[tid * QGRPS + i].y;
    }
    const float var = (SS - S * S / CNT) / (CNT - 1.0f);
    sig[tid] = sqrtf(fmaxf(var, 0.0f));
  }
  __syncthreads();

  if (tid == 0) {
    float acc = 0.f;
    #pragma unroll
    for (int b2 = 0; b2 < 8; ++b2) acc += fmaxf(sig[2 * b2], sig[2 * b2 + 1]);
    out[0] = acc * 0.125f;
  }
}

// ---------------------------------------------------------------------------
extern "C" void kernel_launch(void* const* d_in, const int* in_sizes, int n_in,
                              void* d_out, int out_size, void* d_ws, size_t ws_size,
                              hipStream_t stream) {
  const float* x = (const float*)d_in[0];
  const float* y = (const float*)d_in[1];
  float* out = (float*)d_out;

  char* ws = (char*)d_ws;
  unsigned* keys = (unsigned*)ws;                                    // 4 MB
  unsigned long long* partials = (unsigned long long*)(ws + KEY_BYTES);        // 2 KB
  unsigned* gticks = (unsigned*)(ws + KEY_BYTES + NGROUPS * sizeof(unsigned long long)); // 1 KB
  unsigned* gtick  = gticks + NGROUPS;

  hipLaunchKernelGGL(fused_ticket_kernel, dim3(GRID1), dim3(BLK), 0, stream,
                     x, y, keys, partials, gticks, gtick, out);
}

// Round 9
// 29.421 us; speedup vs baseline: 14.6413x; 12.6910x over previous
//
#include <hip/hip_runtime.h>
#include <math.h>

#define NPTS 4096
#define BLK 256
#define NUNITS 16                    // 8 batches * 2 directions
#define CHUNKS 16                    // target chunks per unit
#define CSZ 256                      // targets per chunk
#define TILES 8                      // 32-target tiles per chunk
#define QGRP 256                     // queries per block (kernel 1)
#define QGRPS 16                     // query groups per unit
#define GRID1 (NUNITS * QGRPS * CHUNKS)  // 4096 blocks
#define GRID2 (NUNITS * QGRPS)           // 256 blocks
#define CNT 12288.0f                 // N*D elements per std
#define KEY_BYTES ((size_t)NUNITS * CHUNKS * NPTS * 4)   // 4 MB

typedef _Float16 half8 __attribute__((ext_vector_type(8)));
typedef float f32x16 __attribute__((ext_vector_type(16)));

__device__ __forceinline__ unsigned umin2(unsigned a, unsigned b) { return a < b ? a : b; }
__device__ __forceinline__ float fmin3(float a, float b, float c) {
  return fminf(fminf(a, b), c);      // fuses to v_min3_f32
}

// min over the 16 f32 accumulator regs of one 32x32 MFMA result
__device__ __forceinline__ float tilemin16(const f32x16 d) {
  const float a0 = fmin3(d[0],  d[1],  d[2]);
  const float a1 = fmin3(d[3],  d[4],  d[5]);
  const float a2 = fmin3(d[6],  d[7],  d[8]);
  const float a3 = fmin3(d[9],  d[10], d[11]);
  const float a4 = fmin3(d[12], d[13], d[14]);
  return fminf(fmin3(a0, a1, a2), fmin3(a3, a4, d[15]));
}

// ---------------------------------------------------------------------------
// Kernel 1 (r5 verbatim — best measured): per (unit, query, chunk)
// hierarchical argmin key. fp16-split d2 via ONE 32x32x16 f16 MFMA per
// 32-target tile:
//  k0-2: bh*(-2ah)  k3-5: bl*(-2ah)  k6-8: bh*(-2al)
//  k9,10: b2{h,l}*1  k11,12: 1*a2{h,l}  k13-15: 0
// Hot loop tracks only (trunc tile-min | tile-id); winning 32-row tile is
// resolved exactly in kernel 2. No fences, no tickets here.
// ---------------------------------------------------------------------------
__global__ __launch_bounds__(BLK, 4) void keys_kernel(
    const float* __restrict__ x, const float* __restrict__ y,
    unsigned* __restrict__ keys) {
  __shared__ half8 Ap[2 * CSZ];    // 8 KB: plane [hi5][256 targets]
  __shared__ half8 Bq[2 * QGRP];   // 8 KB: plane [hi5][256 queries]

  const int bid   = blockIdx.x;
  const int unit  = bid >> 8;          // 256 blocks per unit
  const int qg    = (bid >> 4) & 15;
  const int chunk = bid & 15;
  const int b = unit >> 1, dir = unit & 1;
  const float* __restrict__ Q = (dir ? y : x) + (size_t)b * NPTS * 3;  // queries
  const float* __restrict__ T = (dir ? x : y) + (size_t)b * NPTS * 3;  // targets

  const int tid = threadIdx.x;
  const _Float16 one  = (_Float16)1.0f;
  const _Float16 zero = (_Float16)0.0f;
  const _Float16 n2   = (_Float16)(-2.0f);

  // ---- pack one target row per thread ----
  {
    const int tg = chunk * CSZ + tid;
    const float bx = T[3 * tg], by = T[3 * tg + 1], bz = T[3 * tg + 2];
    const float b2 = fmaf(bx, bx, fmaf(by, by, bz * bz));
    const _Float16 bh0 = (_Float16)bx, bh1 = (_Float16)by, bh2 = (_Float16)bz;
    const _Float16 bl0 = (_Float16)(bx - (float)bh0);
    const _Float16 bl1 = (_Float16)(by - (float)bh1);
    const _Float16 bl2 = (_Float16)(bz - (float)bh2);
    const _Float16 s2h = (_Float16)b2;
    const _Float16 s2l = (_Float16)(b2 - (float)s2h);
    half8 lo, hi;
    lo[0] = bh0; lo[1] = bh1; lo[2] = bh2; lo[3] = bl0;
    lo[4] = bl1; lo[5] = bl2; lo[6] = bh0; lo[7] = bh1;
    hi[0] = bh2; hi[1] = s2h; hi[2] = s2l; hi[3] = one;
    hi[4] = one; hi[5] = zero; hi[6] = zero; hi[7] = zero;
    Ap[tid]       = lo;
    Ap[CSZ + tid] = hi;
  }
  // ---- pack one query column per thread ----
  {
    const int qq = qg * QGRP + tid;
    const float ax = Q[3 * qq], ay = Q[3 * qq + 1], az = Q[3 * qq + 2];
    const float a2 = fmaf(ax, ax, fmaf(ay, ay, az * az));
    const _Float16 ah0 = (_Float16)ax, ah1 = (_Float16)ay, ah2 = (_Float16)az;
    const _Float16 al0 = (_Float16)(ax - (float)ah0);
    const _Float16 al1 = (_Float16)(ay - (float)ah1);
    const _Float16 al2 = (_Float16)(az - (float)ah2);
    const _Float16 a2h = (_Float16)a2;
    const _Float16 a2l = (_Float16)(a2 - (float)a2h);
    half8 lo, hi;
    lo[0] = n2 * ah0; lo[1] = n2 * ah1; lo[2] = n2 * ah2; lo[3] = n2 * ah0;
    lo[4] = n2 * ah1; lo[5] = n2 * ah2; lo[6] = n2 * al0; lo[7] = n2 * al1;
    hi[0] = n2 * al2; hi[1] = one; hi[2] = one; hi[3] = a2h;
    hi[4] = a2l; hi[5] = zero; hi[6] = zero; hi[7] = zero;
    Bq[tid]        = lo;
    Bq[QGRP + tid] = hi;
  }
  __syncthreads();

  const int lane = tid & 63, w = tid >> 6, ln = lane & 31, hi5 = lane >> 5;
  // wave w owns queries w*64 .. w*64+63 (2 column tiles)
  const half8 bf0 = Bq[hi5 * QGRP + w * 64 + ln];
  const half8 bf1 = Bq[hi5 * QGRP + w * 64 + 32 + ln];

  f32x16 Z;
  #pragma unroll
  for (int r = 0; r < 16; ++r) Z[r] = 0.0f;

  unsigned kacc0 = 0xFFFFFFFFu, kacc1 = 0xFFFFFFFFu;
  const unsigned pbase = (unsigned)(chunk * TILES);

  #pragma unroll
  for (int t = 0; t < TILES; ++t) {
    const half8 af = Ap[hi5 * CSZ + t * 32 + ln];
    const f32x16 d0 = __builtin_amdgcn_mfma_f32_32x32x16_f16(af, bf0, Z, 0, 0, 0);
    const f32x16 d1 = __builtin_amdgcn_mfma_f32_32x32x16_f16(af, bf1, Z, 0, 0, 0);
    const unsigned pay = pbase + (unsigned)t;
    kacc0 = umin2(kacc0, (__float_as_uint(tilemin16(d0)) & 0xFFFFF000u) | pay);
    kacc1 = umin2(kacc1, (__float_as_uint(tilemin16(d1)) & 0xFFFFF000u) | pay);
  }

  // merge the two 16-row halves of each tile (key carries tile-id only)
  kacc0 = umin2(kacc0, (unsigned)__shfl_xor((int)kacc0, 32));
  kacc1 = umin2(kacc1, (unsigned)__shfl_xor((int)kacc1, 32));

  if (lane < 32) {
    const unsigned kb = (unsigned)((unit * CHUNKS + chunk) << 12);
    const unsigned q0 = (unsigned)(qg * QGRP + w * 64 + ln);
    keys[kb | q0]        = kacc0;
    keys[kb | (q0 + 32)] = kacc1;
  }
}

// ---------------------------------------------------------------------------
// Kernel 2 (fused resolve + finalize, fence-light): per query, min the 16
// chunk keys (plain loads — coherent across the dispatch boundary, proven
// r5/r6) -> winning 32-target tile; exact fp32 rescan (first-index
// tie-break); residual; block-reduced (sum,sumsq) published as ONE u64
// atomicExch from tid 0, followed by ONE __threadfence + self-resetting
// mod-256 atomicInc ticket (no init needed, replay-safe from any poison).
// The single last-arriver block re-reads all partials atomically and runs
// the deterministic finalize.
// ---------------------------------------------------------------------------
__global__ __launch_bounds__(BLK) void resolve_finalize_kernel(
    const float* __restrict__ x, const float* __restrict__ y,
    const unsigned* __restrict__ keys,
    unsigned long long* __restrict__ partials,
    unsigned* __restrict__ gtick, float* __restrict__ out) {
  __shared__ float wS[4], wSS[4];
  __shared__ unsigned lastsh;
  __shared__ float2 sh2[GRID2];
  __shared__ float sig[NUNITS];

  const int bid  = blockIdx.x;       // unit*16 + qblk
  const int unit = bid >> 4;
  const int b = unit >> 1, dir = unit & 1;
  const float* __restrict__ Q = (dir ? y : x) + (size_t)b * NPTS * 3;
  const float* __restrict__ T = (dir ? x : y) + (size_t)b * NPTS * 3;
  const int tid = threadIdx.x;
  const int q = ((bid & 15) << 8) + tid;

  unsigned bk = 0xFFFFFFFFu;
  #pragma unroll
  for (int c = 0; c < CHUNKS; ++c) {
    bk = umin2(bk, keys[((unsigned)(unit * CHUNKS + c) << 12) | (unsigned)q]);
  }
  const int tbase = (int)(bk & 4095u) * 32;   // payload = chunk*8 + tile

  const float qx = Q[3 * q], qy = Q[3 * q + 1], qz = Q[3 * q + 2];
  unsigned best = 0xFFFFFFFFu;
  #pragma unroll 8
  for (int i = 0; i < 32; ++i) {
    const int j = tbase + i;
    const float dx = qx - T[3 * j];
    const float dy = qy - T[3 * j + 1];
    const float dz = qz - T[3 * j + 2];
    const float d2 = fmaf(dx, dx, fmaf(dy, dy, dz * dz));
    // exact fp32 in-tile argmin, first-index tie-break (5 low bits = row)
    best = umin2(best, (__float_as_uint(d2) & 0xFFFFFFE0u) | (unsigned)i);
  }
  const int j = tbase + (int)(best & 31u);

  const float rx = qx - T[3 * j];
  const float ry = qy - T[3 * j + 1];
  const float rz = qz - T[3 * j + 2];
  float s  = rx + ry + rz;
  float ss = fmaf(rx, rx, fmaf(ry, ry, rz * rz));

  #pragma unroll
  for (int off = 32; off > 0; off >>= 1) {
    s  += __shfl_down(s, off);
    ss += __shfl_down(ss, off);
  }
  const int wid = tid >> 6;
  if ((tid & 63) == 0) { wS[wid] = s; wSS[wid] = ss; }
  __syncthreads();

  if (tid == 0) {
    const float S  = wS[0]  + wS[1]  + wS[2]  + wS[3];
    const float SS = wSS[0] + wSS[1] + wSS[2] + wSS[3];
    const unsigned long long pv =
        ((unsigned long long)__float_as_uint(SS) << 32) | __float_as_uint(S);
    atomicExch(&partials[bid], pv);     // device-scope publish (cross-XCD safe)
    __threadfence();                    // order publish before ticket (tid 0 only)
    // self-resetting mod-256 ticket: from ANY initial value (incl. poison)
    // exactly one block per run observes old == 254.
    lastsh = atomicInc(gtick, GRID2 - 1u);
  }
  __syncthreads();
  if (lastsh != GRID2 - 2u) return;     // 255/256 blocks exit here

  // ---- last block: deterministic finalize ----
  __threadfence();                      // acquire
  {
    const unsigned long long pv = atomicAdd(&partials[tid], 0ULL);  // coherent read
    sh2[tid] = make_float2(__uint_as_float((unsigned)(pv & 0xFFFFFFFFull)),
                           __uint_as_float((unsigned)(pv >> 32)));
  }
  __syncthreads();

  if (tid < NUNITS) {
    float S = 0.f, SS = 0.f;
    #pragma unroll
    for (int i = 0; i < QGRPS; ++i) {
      S  += sh2[tid * QGRPS + i].x;
      SS += sh2[tid * QGRPS + i].y;
    }
    const float var = (SS - S * S / CNT) / (CNT - 1.0f);
    sig[tid] = sqrtf(fmaxf(var, 0.0f));
  }
  __syncthreads();

  if (tid == 0) {
    float acc = 0.f;
    #pragma unroll
    for (int b2 = 0; b2 < 8; ++b2) acc += fmaxf(sig[2 * b2], sig[2 * b2 + 1]);
    out[0] = acc * 0.125f;
  }
}

// ---------------------------------------------------------------------------
extern "C" void kernel_launch(void* const* d_in, const int* in_sizes, int n_in,
                              void* d_out, int out_size, void* d_ws, size_t ws_size,
                              hipStream_t stream) {
  const float* x = (const float*)d_in[0];
  const float* y = (const float*)d_in[1];
  float* out = (float*)d_out;

  char* ws = (char*)d_ws;
  unsigned* keys = (unsigned*)ws;                                          // 4 MB
  unsigned long long* partials = (unsigned long long*)(ws + KEY_BYTES);    // 2 KB
  unsigned* gtick = (unsigned*)(ws + KEY_BYTES + GRID2 * sizeof(unsigned long long));

  hipLaunchKernelGGL(keys_kernel, dim3(GRID1), dim3(BLK), 0, stream, x, y, keys);
  hipLaunchKernelGGL(resolve_finalize_kernel, dim3(GRID2), dim3(BLK), 0, stream,
                     x, y, keys, partials, gtick, out);
}

// Round 10
// 25.110 us; speedup vs baseline: 17.1550x; 1.1717x over previous
//
#include <hip/hip_runtime.h>
#include <math.h>

#define NPTS 4096
#define BLK 256
#define NUNITS 16                    // 8 batches * 2 directions
#define CHUNKS 16                    // target chunks per unit
#define CSZ 256                      // targets per chunk
#define TILES 8                      // 32-target tiles per chunk
#define QGRP 512                     // queries per block (kernel 1)
#define QGRPS 8                      // query groups per unit (kernel 1)
#define GRID1 (NUNITS * QGRPS * CHUNKS)  // 2048 blocks
#define GRID2 (NUNITS * 16)              // 256 blocks (resolve: 256 q each)
#define CNT 12288.0f                 // N*D elements per std
#define KEY_BYTES ((size_t)NUNITS * CHUNKS * NPTS * 4)   // 4 MB

typedef _Float16 half8 __attribute__((ext_vector_type(8)));
typedef float f32x16 __attribute__((ext_vector_type(16)));

__device__ __forceinline__ unsigned umin2(unsigned a, unsigned b) { return a < b ? a : b; }
__device__ __forceinline__ float fmin3(float a, float b, float c) {
  return fminf(fminf(a, b), c);      // fuses to v_min3_f32
}

// min over the 16 f32 accumulator regs of one 32x32 MFMA result
__device__ __forceinline__ float tilemin16(const f32x16 d) {
  const float a0 = fmin3(d[0],  d[1],  d[2]);
  const float a1 = fmin3(d[3],  d[4],  d[5]);
  const float a2 = fmin3(d[6],  d[7],  d[8]);
  const float a3 = fmin3(d[9],  d[10], d[11]);
  const float a4 = fmin3(d[12], d[13], d[14]);
  return fminf(fmin3(a0, a1, a2), fmin3(a3, a4, d[15]));
}

// ---------------------------------------------------------------------------
// Kernel 1: per (unit, qgrp, chunk) hierarchical argmin keys.
// r5's proven hot loop, re-geometried: 512 queries/block so each af ds_read
// and tile payload feeds 4 MFMAs (was 2), grid 2048 (was 4096), 24 KB LDS ->
// 6 blocks/CU -> 6 waves/SIMD (was 4) for latency hiding.
// fp16-split d2 via ONE 32x32x16 f16 MFMA per 32-target tile:
//  k0-2: bh*(-2ah)  k3-5: bl*(-2ah)  k6-8: bh*(-2al)
//  k9,10: b2{h,l}*1  k11,12: 1*a2{h,l}  k13-15: 0
// Hot loop tracks only (trunc tile-min | tile-id); exact resolve in kernel 2.
// ---------------------------------------------------------------------------
__global__ __launch_bounds__(BLK, 4) void keys_kernel(
    const float* __restrict__ x, const float* __restrict__ y,
    unsigned* __restrict__ keys) {
  __shared__ half8 Ap[2 * CSZ];    //  8 KB: plane [hi5][256 targets]
  __shared__ half8 Bq[2 * QGRP];   // 16 KB: plane [hi5][512 queries]

  const int bid   = blockIdx.x;
  const int unit  = bid >> 7;          // 8 qgrps * 16 chunks = 128 blocks/unit
  const int qg    = (bid >> 4) & 7;
  const int chunk = bid & 15;
  const int b = unit >> 1, dir = unit & 1;
  const float* __restrict__ Q = (dir ? y : x) + (size_t)b * NPTS * 3;  // queries
  const float* __restrict__ T = (dir ? x : y) + (size_t)b * NPTS * 3;  // targets

  const int tid = threadIdx.x;
  const _Float16 one  = (_Float16)1.0f;
  const _Float16 zero = (_Float16)0.0f;
  const _Float16 n2   = (_Float16)(-2.0f);

  // ---- pack one target row per thread ----
  {
    const int tg = chunk * CSZ + tid;
    const float bx = T[3 * tg], by = T[3 * tg + 1], bz = T[3 * tg + 2];
    const float b2 = fmaf(bx, bx, fmaf(by, by, bz * bz));
    const _Float16 bh0 = (_Float16)bx, bh1 = (_Float16)by, bh2 = (_Float16)bz;
    const _Float16 bl0 = (_Float16)(bx - (float)bh0);
    const _Float16 bl1 = (_Float16)(by - (float)bh1);
    const _Float16 bl2 = (_Float16)(bz - (float)bh2);
    const _Float16 s2h = (_Float16)b2;
    const _Float16 s2l = (_Float16)(b2 - (float)s2h);
    half8 lo, hi;
    lo[0] = bh0; lo[1] = bh1; lo[2] = bh2; lo[3] = bl0;
    lo[4] = bl1; lo[5] = bl2; lo[6] = bh0; lo[7] = bh1;
    hi[0] = bh2; hi[1] = s2h; hi[2] = s2l; hi[3] = one;
    hi[4] = one; hi[5] = zero; hi[6] = zero; hi[7] = zero;
    Ap[tid]       = lo;
    Ap[CSZ + tid] = hi;
  }
  // ---- pack two query columns per thread ----
  #pragma unroll
  for (int k = 0; k < 2; ++k) {
    const int i  = tid + k * BLK;      // 0..511
    const int qq = qg * QGRP + i;
    const float ax = Q[3 * qq], ay = Q[3 * qq + 1], az = Q[3 * qq + 2];
    const float a2 = fmaf(ax, ax, fmaf(ay, ay, az * az));
    const _Float16 ah0 = (_Float16)ax, ah1 = (_Float16)ay, ah2 = (_Float16)az;
    const _Float16 al0 = (_Float16)(ax - (float)ah0);
    const _Float16 al1 = (_Float16)(ay - (float)ah1);
    const _Float16 al2 = (_Float16)(az - (float)ah2);
    const _Float16 a2h = (_Float16)a2;
    const _Float16 a2l = (_Float16)(a2 - (float)a2h);
    half8 lo, hi;
    lo[0] = n2 * ah0; lo[1] = n2 * ah1; lo[2] = n2 * ah2; lo[3] = n2 * ah0;
    lo[4] = n2 * ah1; lo[5] = n2 * ah2; lo[6] = n2 * al0; lo[7] = n2 * al1;
    hi[0] = n2 * al2; hi[1] = one; hi[2] = one; hi[3] = a2h;
    hi[4] = a2l; hi[5] = zero; hi[6] = zero; hi[7] = zero;
    Bq[i]        = lo;
    Bq[QGRP + i] = hi;
  }
  __syncthreads();

  const int lane = tid & 63, w = tid >> 6, ln = lane & 31, hi5 = lane >> 5;
  // wave w owns queries w*128 .. w*128+127 (4 column tiles)
  const half8 bf0 = Bq[hi5 * QGRP + w * 128 + ln];
  const half8 bf1 = Bq[hi5 * QGRP + w * 128 + 32 + ln];
  const half8 bf2 = Bq[hi5 * QGRP + w * 128 + 64 + ln];
  const half8 bf3 = Bq[hi5 * QGRP + w * 128 + 96 + ln];

  f32x16 Z;
  #pragma unroll
  for (int r = 0; r < 16; ++r) Z[r] = 0.0f;

  unsigned kacc0 = 0xFFFFFFFFu, kacc1 = 0xFFFFFFFFu;
  unsigned kacc2 = 0xFFFFFFFFu, kacc3 = 0xFFFFFFFFu;
  const unsigned pbase = (unsigned)(chunk * TILES);

  #pragma unroll
  for (int t = 0; t < TILES; ++t) {
    const half8 af = Ap[hi5 * CSZ + t * 32 + ln];   // one read feeds 4 MFMAs
    const f32x16 d0 = __builtin_amdgcn_mfma_f32_32x32x16_f16(af, bf0, Z, 0, 0, 0);
    const f32x16 d1 = __builtin_amdgcn_mfma_f32_32x32x16_f16(af, bf1, Z, 0, 0, 0);
    const f32x16 d2 = __builtin_amdgcn_mfma_f32_32x32x16_f16(af, bf2, Z, 0, 0, 0);
    const f32x16 d3 = __builtin_amdgcn_mfma_f32_32x32x16_f16(af, bf3, Z, 0, 0, 0);
    const unsigned pay = pbase + (unsigned)t;
    kacc0 = umin2(kacc0, (__float_as_uint(tilemin16(d0)) & 0xFFFFF000u) | pay);
    kacc1 = umin2(kacc1, (__float_as_uint(tilemin16(d1)) & 0xFFFFF000u) | pay);
    kacc2 = umin2(kacc2, (__float_as_uint(tilemin16(d2)) & 0xFFFFF000u) | pay);
    kacc3 = umin2(kacc3, (__float_as_uint(tilemin16(d3)) & 0xFFFFF000u) | pay);
  }

  // merge the two 16-row halves of each tile (key carries tile-id only)
  kacc0 = umin2(kacc0, (unsigned)__shfl_xor((int)kacc0, 32));
  kacc1 = umin2(kacc1, (unsigned)__shfl_xor((int)kacc1, 32));
  kacc2 = umin2(kacc2, (unsigned)__shfl_xor((int)kacc2, 32));
  kacc3 = umin2(kacc3, (unsigned)__shfl_xor((int)kacc3, 32));

  if (lane < 32) {
    const unsigned kb = (unsigned)((unit * CHUNKS + chunk) << 12);
    const unsigned q0 = (unsigned)(qg * QGRP + w * 128 + ln);
    keys[kb | q0]        = kacc0;
    keys[kb | (q0 + 32)] = kacc1;
    keys[kb | (q0 + 64)] = kacc2;
    keys[kb | (q0 + 96)] = kacc3;
  }
}

// ---------------------------------------------------------------------------
// Kernel 2 (r5 verbatim): per query, min the 16 chunk keys -> winning
// 32-target tile; re-scan that tile in exact fp32 (first-index tie-break),
// residual, deterministic per-block (sum, sumsq) partial.
// ---------------------------------------------------------------------------
__global__ __launch_bounds__(BLK) void resolve_kernel(
    const float* __restrict__ x, const float* __restrict__ y,
    const unsigned* __restrict__ keys, float2* __restrict__ partials) {
  __shared__ float wS[4], wSS[4];

  const int bid  = blockIdx.x;       // unit*16 + qblk
  const int unit = bid >> 4;
  const int b = unit >> 1, dir = unit & 1;
  const float* __restrict__ Q = (dir ? y : x) + (size_t)b * NPTS * 3;
  const float* __restrict__ T = (dir ? x : y) + (size_t)b * NPTS * 3;
  const int q = ((bid & 15) << 8) + (int)threadIdx.x;

  unsigned bk = 0xFFFFFFFFu;
  #pragma unroll
  for (int c = 0; c < CHUNKS; ++c) {
    bk = umin2(bk, keys[((unsigned)(unit * CHUNKS + c) << 12) | (unsigned)q]);
  }
  const int tbase = (int)(bk & 4095u) * 32;   // payload = chunk*8 + tile

  const float qx = Q[3 * q], qy = Q[3 * q + 1], qz = Q[3 * q + 2];
  unsigned best = 0xFFFFFFFFu;
  #pragma unroll 8
  for (int i = 0; i < 32; ++i) {
    const int j = tbase + i;
    const float dx = qx - T[3 * j];
    const float dy = qy - T[3 * j + 1];
    const float dz = qz - T[3 * j + 2];
    const float d2 = fmaf(dx, dx, fmaf(dy, dy, dz * dz));
    // exact fp32 in-tile argmin, first-index tie-break (5 low bits = row)
    best = umin2(best, (__float_as_uint(d2) & 0xFFFFFFE0u) | (unsigned)i);
  }
  const int j = tbase + (int)(best & 31u);

  const float rx = qx - T[3 * j];
  const float ry = qy - T[3 * j + 1];
  const float rz = qz - T[3 * j + 2];
  float s  = rx + ry + rz;
  float ss = fmaf(rx, rx, fmaf(ry, ry, rz * rz));

  #pragma unroll
  for (int off = 32; off > 0; off >>= 1) {
    s  += __shfl_down(s, off);
    ss += __shfl_down(ss, off);
  }
  const int wid = threadIdx.x >> 6;
  if ((threadIdx.x & 63) == 0) { wS[wid] = s; wSS[wid] = ss; }
  __syncthreads();
  if (threadIdx.x == 0) {
    partials[bid] = make_float2(wS[0] + wS[1] + wS[2] + wS[3],
                                wSS[0] + wSS[1] + wSS[2] + wSS[3]);
  }
}

// ---------------------------------------------------------------------------
// Kernel 3 (r5 verbatim): deterministic finalize.
// ---------------------------------------------------------------------------
__global__ __launch_bounds__(256) void finalize_kernel(
    const float2* __restrict__ partials, float* __restrict__ out) {
  __shared__ float2 sh[GRID2];
  __shared__ float sig[NUNITS];

  sh[threadIdx.x] = partials[threadIdx.x];
  __syncthreads();

  if (threadIdx.x < NUNITS) {
    float S = 0.f, SS = 0.f;
    #pragma unroll
    for (int i = 0; i < 16; ++i) {
      S  += sh[threadIdx.x * 16 + i].x;
      SS += sh[threadIdx.x * 16 + i].y;
    }
    const float var = (SS - S * S / CNT) / (CNT - 1.0f);
    sig[threadIdx.x] = sqrtf(fmaxf(var, 0.0f));
  }
  __syncthreads();

  if (threadIdx.x == 0) {
    float acc = 0.f;
    #pragma unroll
    for (int b = 0; b < 8; ++b) acc += fmaxf(sig[2 * b], sig[2 * b + 1]);
    out[0] = acc * 0.125f;
  }
}

// ---------------------------------------------------------------------------
extern "C" void kernel_launch(void* const* d_in, const int* in_sizes, int n_in,
                              void* d_out, int out_size, void* d_ws, size_t ws_size,
                              hipStream_t stream) {
  const float* x = (const float*)d_in[0];
  const float* y = (const float*)d_in[1];
  float* out = (float*)d_out;

  unsigned* keys    = (unsigned*)d_ws;                       // 4 MB
  float2*  partials = (float2*)((char*)d_ws + KEY_BYTES);    // 2 KB

  hipLaunchKernelGGL(keys_kernel, dim3(GRID1), dim3(BLK), 0, stream, x, y, keys);
  hipLaunchKernelGGL(resolve_kernel, dim3(GRID2), dim3(BLK), 0, stream,
                     x, y, keys, partials);
  hipLaunchKernelGGL(finalize_kernel, dim3(1), dim3(256), 0, stream, partials, out);
}

// Round 11
// 23.289 us; speedup vs baseline: 18.4960x; 1.0782x over previous
//
#include <hip/hip_runtime.h>
#include <math.h>

#define NPTS 4096
#define BLK 256
#define NUNITS 16                    // 8 batches * 2 directions
#define QGRP 128                     // queries per block
#define QGRPS 32                     // query groups per unit
#define GRID1 (NUNITS * QGRPS)       // 512 blocks (2 per CU)
#define PHT 2048                     // targets staged per LDS phase
#define CNT 12288.0f                 // N*D elements per std

typedef _Float16 half8 __attribute__((ext_vector_type(8)));
typedef float f32x16 __attribute__((ext_vector_type(16)));

__device__ __forceinline__ unsigned umin2(unsigned a, unsigned b) { return a < b ? a : b; }
__device__ __forceinline__ float fmin3(float a, float b, float c) {
  return fminf(fminf(a, b), c);      // fuses to v_min3_f32
}

// min over the 16 f32 accumulator regs of one 32x32 MFMA result
__device__ __forceinline__ float tilemin16(const f32x16 d) {
  const float a0 = fmin3(d[0],  d[1],  d[2]);
  const float a1 = fmin3(d[3],  d[4],  d[5]);
  const float a2 = fmin3(d[6],  d[7],  d[8]);
  const float a3 = fmin3(d[9],  d[10], d[11]);
  const float a4 = fmin3(d[12], d[13], d[14]);
  return fminf(fmin3(a0, a1, a2), fmin3(a3, a4, d[15]));
}

// ---------------------------------------------------------------------------
// Kernel 1: FULL-SCAN fused NN. Block = (unit, 128-query group); scans all
// 4096 targets in two 2048-target LDS phases, so the hierarchical argmin key
// (trunc tile-min d2 | tile-id, proven r5-r10) is FINAL in-block: no keys
// round-trip, no resolve dispatch. lane<32 rescans its query's winning
// 32-target tile from L2 in exact fp32 (first-index tie-break) and the block
// emits one float2 (sum, sumsq) partial.
// fp16-split d2 via ONE 32x32x16 f16 MFMA per tile (proven r3+):
//  k0-2: bh*(-2ah)  k3-5: bl*(-2ah)  k6-8: bh*(-2al)
//  k9,10: b2{h,l}*1  k11,12: 1*a2{h,l}  k13-15: 0
// ---------------------------------------------------------------------------
__global__ __launch_bounds__(BLK, 2) void fullscan_kernel(
    const float* __restrict__ x, const float* __restrict__ y,
    float2* __restrict__ partials) {
  __shared__ half8 Ap[2 * PHT];    // 64 KB: plane [hi5][2048 targets]
  __shared__ half8 Bq[2 * QGRP];   //  4 KB: plane [hi5][128 queries]
  __shared__ float wS[4], wSS[4];

  const int bid  = blockIdx.x;
  const int unit = bid >> 5, qg = bid & 31;
  const int b = unit >> 1, dir = unit & 1;
  const float* __restrict__ Q = (dir ? y : x) + (size_t)b * NPTS * 3;  // queries
  const float* __restrict__ T = (dir ? x : y) + (size_t)b * NPTS * 3;  // targets

  const int tid = threadIdx.x;
  const _Float16 one  = (_Float16)1.0f;
  const _Float16 zero = (_Float16)0.0f;
  const _Float16 n2   = (_Float16)(-2.0f);

  // ---- pack this block's 128 queries (threads 0..127) ----
  if (tid < QGRP) {
    const int qq = qg * QGRP + tid;
    const float ax = Q[3 * qq], ay = Q[3 * qq + 1], az = Q[3 * qq + 2];
    const float a2 = fmaf(ax, ax, fmaf(ay, ay, az * az));
    const _Float16 ah0 = (_Float16)ax, ah1 = (_Float16)ay, ah2 = (_Float16)az;
    const _Float16 al0 = (_Float16)(ax - (float)ah0);
    const _Float16 al1 = (_Float16)(ay - (float)ah1);
    const _Float16 al2 = (_Float16)(az - (float)ah2);
    const _Float16 a2h = (_Float16)a2;
    const _Float16 a2l = (_Float16)(a2 - (float)a2h);
    half8 lo, hi;
    lo[0] = n2 * ah0; lo[1] = n2 * ah1; lo[2] = n2 * ah2; lo[3] = n2 * ah0;
    lo[4] = n2 * ah1; lo[5] = n2 * ah2; lo[6] = n2 * al0; lo[7] = n2 * al1;
    hi[0] = n2 * al2; hi[1] = one; hi[2] = one; hi[3] = a2h;
    hi[4] = a2l; hi[5] = zero; hi[6] = zero; hi[7] = zero;
    Bq[tid]        = lo;
    Bq[QGRP + tid] = hi;
  }

  const int lane = tid & 63, w = tid >> 6, ln = lane & 31, hi5 = lane >> 5;
  unsigned kacc0 = 0xFFFFFFFFu, kacc1 = 0xFFFFFFFFu;
  f32x16 Z;
  #pragma unroll
  for (int r = 0; r < 16; ++r) Z[r] = 0.0f;

  half8 bf;
  for (int c = 0; c < 2; ++c) {
    __syncthreads();   // c=0: nothing to protect yet; c=1: all waves done with Ap
    // ---- stage 2048 targets into LDS (8 per thread) ----
    #pragma unroll
    for (int k = 0; k < 8; ++k) {
      const int i  = tid + k * BLK;          // 0..2047
      const int tg = c * PHT + i;
      const float bx = T[3 * tg], by = T[3 * tg + 1], bz = T[3 * tg + 2];
      const float b2 = fmaf(bx, bx, fmaf(by, by, bz * bz));
      const _Float16 bh0 = (_Float16)bx, bh1 = (_Float16)by, bh2 = (_Float16)bz;
      const _Float16 bl0 = (_Float16)(bx - (float)bh0);
      const _Float16 bl1 = (_Float16)(by - (float)bh1);
      const _Float16 bl2 = (_Float16)(bz - (float)bh2);
      const _Float16 s2h = (_Float16)b2;
      const _Float16 s2l = (_Float16)(b2 - (float)s2h);
      half8 lo, hi;
      lo[0] = bh0; lo[1] = bh1; lo[2] = bh2; lo[3] = bl0;
      lo[4] = bl1; lo[5] = bl2; lo[6] = bh0; lo[7] = bh1;
      hi[0] = bh2; hi[1] = s2h; hi[2] = s2l; hi[3] = one;
      hi[4] = one; hi[5] = zero; hi[6] = zero; hi[7] = zero;
      Ap[i]       = lo;
      Ap[PHT + i] = hi;
    }
    __syncthreads();
    if (c == 0) bf = Bq[hi5 * QGRP + w * 32 + ln];   // wave w owns one col tile

    const unsigned cb = (unsigned)(c * (PHT / 32));
    #pragma unroll 4
    for (int t = 0; t < PHT / 32; ++t) {             // 64 tiles per phase
      const half8 af = Ap[hi5 * PHT + t * 32 + ln];
      const f32x16 d = __builtin_amdgcn_mfma_f32_32x32x16_f16(af, bf, Z, 0, 0, 0);
      const unsigned key = (__float_as_uint(tilemin16(d)) & 0xFFFFF000u) | (cb + (unsigned)t);
      if (t & 1) kacc1 = umin2(kacc1, key);
      else       kacc0 = umin2(kacc0, key);
    }
  }
  unsigned kacc = umin2(kacc0, kacc1);
  kacc = umin2(kacc, (unsigned)__shfl_xor((int)kacc, 32));   // merge 16-row halves

  // ---- exact fp32 rescan of the winning 32-target tile (lane < 32) ----
  float s = 0.f, ss = 0.f;
  if (lane < 32) {
    const int q = qg * QGRP + w * 32 + ln;
    const int tbase = (int)(kacc & 4095u) * 32;      // payload = global tile id
    const float qx = Q[3 * q], qy = Q[3 * q + 1], qz = Q[3 * q + 2];
    unsigned best = 0xFFFFFFFFu;
    #pragma unroll 8
    for (int i = 0; i < 32; ++i) {
      const int j = tbase + i;
      const float dx = qx - T[3 * j];
      const float dy = qy - T[3 * j + 1];
      const float dz = qz - T[3 * j + 2];
      const float d2 = fmaf(dx, dx, fmaf(dy, dy, dz * dz));
      best = umin2(best, (__float_as_uint(d2) & 0xFFFFFFE0u) | (unsigned)i);
    }
    const int j = tbase + (int)(best & 31u);
    const float rx = qx - T[3 * j];
    const float ry = qy - T[3 * j + 1];
    const float rz = qz - T[3 * j + 2];
    s  = rx + ry + rz;
    ss = fmaf(rx, rx, fmaf(ry, ry, rz * rz));
  }

  #pragma unroll
  for (int off = 32; off > 0; off >>= 1) {
    s  += __shfl_down(s, off);
    ss += __shfl_down(ss, off);
  }
  if ((tid & 63) == 0) { wS[w] = s; wSS[w] = ss; }
  __syncthreads();
  if (tid == 0) {
    partials[bid] = make_float2(wS[0] + wS[1] + wS[2] + wS[3],
                                wSS[0] + wSS[1] + wSS[2] + wSS[3]);
  }
}

// ---------------------------------------------------------------------------
// Kernel 2: deterministic finalize over 512 partials (32 per unit).
// ---------------------------------------------------------------------------
__global__ __launch_bounds__(BLK) void finalize_kernel(
    const float2* __restrict__ partials, float* __restrict__ out) {
  __shared__ float2 sh[GRID1];
  __shared__ float sig[NUNITS];

  sh[threadIdx.x]       = partials[threadIdx.x];
  sh[threadIdx.x + BLK] = partials[threadIdx.x + BLK];
  __syncthreads();

  if (threadIdx.x < NUNITS) {
    float S = 0.f, SS = 0.f;
    #pragma unroll
    for (int i = 0; i < QGRPS; ++i) {
      S  += sh[threadIdx.x * QGRPS + i].x;
      SS += sh[threadIdx.x * QGRPS + i].y;
    }
    const float var = (SS - S * S / CNT) / (CNT - 1.0f);
    sig[threadIdx.x] = sqrtf(fmaxf(var, 0.0f));
  }
  __syncthreads();

  if (threadIdx.x == 0) {
    float acc = 0.f;
    #pragma unroll
    for (int b = 0; b < 8; ++b) acc += fmaxf(sig[2 * b], sig[2 * b + 1]);
    out[0] = acc * 0.125f;
  }
}

// ---------------------------------------------------------------------------
extern "C" void kernel_launch(void* const* d_in, const int* in_sizes, int n_in,
                              void* d_out, int out_size, void* d_ws, size_t ws_size,
                              hipStream_t stream) {
  const float* x = (const float*)d_in[0];
  const float* y = (const float*)d_in[1];
  float* out = (float*)d_out;
  float2* partials = (float2*)d_ws;   // 512 * 8 B = 4 KB scratch

  hipLaunchKernelGGL(fullscan_kernel, dim3(GRID1), dim3(BLK), 0, stream,
                     x, y, partials);
  hipLaunchKernelGGL(finalize_kernel, dim3(1), dim3(BLK), 0, stream,
                     partials, out);
}